// Round 10
// baseline (352.266 us; speedup 1.0000x reference)
//
#include <hip/hip_runtime.h>
#include <hip/hip_bf16.h>
#include <math.h>

#define TT 2048
#define BB 8
#define DD 128
#define HH 4
#define BT (BB*TT)
#define BH (BB*HH)
#define SCALE 0.1767766952966369f
#define S2LOG (SCALE * 1.4426950408889634f)   // scale * log2(e)

typedef __attribute__((ext_vector_type(8))) short short8;
typedef __attribute__((ext_vector_type(4))) short short4v;
typedef __attribute__((ext_vector_type(4))) float f32x4;
typedef __attribute__((ext_vector_type(2))) float f32x2;
typedef __attribute__((ext_vector_type(4))) unsigned u32x4;
typedef __attribute__((ext_vector_type(2))) unsigned u32x2;
typedef __hip_bfloat16 bf16;

#define MFMA16(a,b,c) __builtin_amdgcn_mfma_f32_16x16x32_bf16(a,b,c,0,0,0)

static __device__ inline short8 ldg8(const bf16* p) {
  return *reinterpret_cast<const short8*>(p);
}
static __device__ inline short4v ldg4(const bf16* p) {
  return *reinterpret_cast<const short4v*>(p);
}
static __device__ inline short f2bs(float x) {
  bf16 h = __float2bfloat16(x);
  return *reinterpret_cast<short*>(&h);
}
// single-instruction pack: two f32 -> one u32 holding {bf16(lo) | bf16(hi)<<16}
static __device__ inline unsigned cvtpk(float lo, float hi) {
  unsigned r;
  asm("v_cvt_pk_bf16_f32 %0, %1, %2" : "=v"(r) : "v"(lo), "v"(hi));
  return r;
}
// load 8 contiguous f32 from global, convert to bf16 A/B-fragment
static __device__ inline short8 ldcvt8(const float* p) {
  f32x4 f0 = *reinterpret_cast<const f32x4*>(p);
  f32x4 f1 = *reinterpret_cast<const f32x4*>(p + 4);
  short8 r;
  #pragma unroll
  for (int i = 0; i < 4; ++i) { r[i] = f2bs(f0[i]); r[4+i] = f2bs(f1[i]); }
  return r;
}

// ---------------- Kernel 1: MFMA projections (unchanged) -------------------
__global__ __launch_bounds__(256) void proj_kernel(
    const float* __restrict__ lob, const float* __restrict__ hawkes,
    const float* __restrict__ Wp, const float* __restrict__ bp,
    const float* __restrict__ Win, const float* __restrict__ binp,
    bf16* __restrict__ qg, bf16* __restrict__ kg, bf16* __restrict__ vtg) {
  __shared__ bf16 hT[32*136];   // h tile; reused as q staging after ah read
  __shared__ bf16 sK[32*136];   // k staging
  __shared__ bf16 vT[128*40];   // v^T staging
  int tid = threadIdx.x;
  int wave = tid >> 6, lane = tid & 63;
  int lr = lane & 15, lq = lane >> 4;
  int r0 = blockIdx.x * 32;
  int b  = r0 >> 11, t0 = r0 & 2047;
  f32x4 z = {0.f,0.f,0.f,0.f};

  short8 alob[2][4], ahk[2];
  #pragma unroll
  for (int mt = 0; mt < 2; ++mt) {
    const float* lp = lob + (size_t)(r0 + mt*16 + lr)*128;
    #pragma unroll
    for (int kt = 0; kt < 4; ++kt) alob[mt][kt] = ldcvt8(lp + kt*32 + lq*8);
    ahk[mt] = ldcvt8(hawkes + (size_t)(r0 + mt*16 + lr)*32 + lq*8);
  }

  for (int nt = wave; nt < 8; nt += 4) {
    int cn = nt*16;
    short8 bfrag = ldcvt8(Wp + (size_t)(cn + lr)*32 + lq*8);
    float bias = bp[cn + lr];
    #pragma unroll
    for (int mt = 0; mt < 2; ++mt) {
      f32x4 c = MFMA16(ahk[mt], bfrag, z);
      #pragma unroll
      for (int r = 0; r < 4; ++r)
        hT[(mt*16 + lq*4 + r)*136 + cn + lr] = __float2bfloat16(c[r] + bias);
    }
  }
  __syncthreads();

  short8 ah[2][4];
  #pragma unroll
  for (int mt = 0; mt < 2; ++mt)
    #pragma unroll
    for (int kt = 0; kt < 4; ++kt)
      ah[mt][kt] = *reinterpret_cast<const short8*>(&hT[(mt*16 + lr)*136 + kt*32 + lq*8]);
  __syncthreads();   // hT free -> reuse as q staging

  for (int nt = wave; nt < 24; nt += 4) {
    int which = nt >> 3;
    int c = (nt & 7)*16 + lr;
    const float* wrow = Win + (size_t)(which*128 + c)*128;
    float bias = binp[which*128 + c];
    f32x4 acc0 = z, acc1 = z;
    #pragma unroll
    for (int kt = 0; kt < 4; ++kt) {
      short8 bfrag = ldcvt8(wrow + kt*32 + lq*8);
      if (which == 0) {
        acc0 = MFMA16(alob[0][kt], bfrag, acc0);
        acc1 = MFMA16(alob[1][kt], bfrag, acc1);
      } else {
        acc0 = MFMA16(ah[0][kt], bfrag, acc0);
        acc1 = MFMA16(ah[1][kt], bfrag, acc1);
      }
    }
    #pragma unroll
    for (int mt = 0; mt < 2; ++mt) {
      f32x4 acc = mt ? acc1 : acc0;
      #pragma unroll
      for (int r = 0; r < 4; ++r) {
        int row = mt*16 + lq*4 + r;
        float val = acc[r] + bias;
        if (which == 0)      hT[row*136 + c] = __float2bfloat16(val);
        else if (which == 1) sK[row*136 + c] = __float2bfloat16(val);
        else                 vT[c*40 + row]  = __float2bfloat16(val);
      }
    }
  }
  __syncthreads();

  // q,k writeout: 256 threads x 32B, fully contiguous 4KB per head
  {
    int head = tid >> 6, tt = (tid >> 1) & 31, half = tid & 1;
    const bf16* sq = &hT[tt*136 + head*32 + half*16];
    const bf16* sk = &sK[tt*136 + head*32 + half*16];
    bf16* qdst = qg + ((size_t)(b*HH + head)*TT + t0 + tt)*32 + half*16;
    bf16* kdst = kg + ((size_t)(b*HH + head)*TT + t0 + tt)*32 + half*16;
    *reinterpret_cast<short8*>(qdst)     = *reinterpret_cast<const short8*>(sq);
    *reinterpret_cast<short8*>(qdst + 8) = *reinterpret_cast<const short8*>(sq + 8);
    *reinterpret_cast<short8*>(kdst)     = *reinterpret_cast<const short8*>(sk);
    *reinterpret_cast<short8*>(kdst + 8) = *reinterpret_cast<const short8*>(sk + 8);
  }
  // v writeout: 128 dd-rows x 32 t, coalesced 16B stores
  {
    int dd = tid >> 1, half = tid & 1;
    int bh = b*HH + (dd >> 5);
    short8 s0 = *reinterpret_cast<const short8*>(&vT[dd*40 + half*16]);
    short8 s1 = *reinterpret_cast<const short8*>(&vT[dd*40 + half*16 + 8]);
    bf16* dst = vtg + ((size_t)bh*32 + (dd & 31))*TT + t0 + half*16;
    *reinterpret_cast<short8*>(dst) = s0;
    *reinterpret_cast<short8*>(dst + 8) = s1;
  }
}

// ------- Kernel 2: fused attention + out-proj + residual + LayerNorm -------
// 16 q-rows/block, 1024 blocks, 8 waves = (head, k-parity half).
// Occupancy: 4 blocks/CU x 8 waves = 32 waves/CU cap (LDS 18KB, small VGPR).
// P staged in LDS as PACKED BF16 (cvt_pk outputs, 2x ds_write_b64), double-
// buffered -> ONE barrier per chunk step. Mean phase: all 512 threads
// handle the combined 16x64 tile (both halves' chunks) -> 256B-contiguous
// row stores. PV from registers (permuted-k). Register double-buffer
// prefetch of next chunk's K AND V throughout.
__global__ __launch_bounds__(512) void attn_kernel(const bf16* __restrict__ qg,
    const bf16* __restrict__ kg, const bf16* __restrict__ vtg,
    float* __restrict__ attn_out, const float* __restrict__ lobf,
    const float* __restrict__ Wo, const float* __restrict__ bo,
    const float* __restrict__ gamma, const float* __restrict__ beta,
    float* __restrict__ outg) {
  // XCD swizzle: 1024 blocks = 8 XCDs x 128; each XCD owns one batch b.
  int wgid = (blockIdx.x & 7)*128 + (blockIdx.x >> 3);
  int b = wgid >> 7, qt = wgid & 127;          // qt: 16-row tile index
  int tid = threadIdx.x;
  int wave = tid >> 6, lane = tid & 63;
  int head = wave & 3, half = wave >> 2;
  int lr = lane & 15, lq = lane >> 4;
  int bh = b*HH + head;
  // P store: [buf][half][head][16 rows x 18 u32 (36 bf16)] = 4608 u32 = 18432B
  __shared__ unsigned plds[4608];
  const bf16* qp = qg + ((size_t)bh*TT + (size_t)qt*16)*32;
  const bf16* kb = kg + (size_t)bh*TT*32;
  const bf16* vb = vtg + (size_t)bh*32*TT;
  f32x4 z = {0.f,0.f,0.f,0.f};

  // Q B-frag: lane holds Q[q=lr][d=lq*8+j]
  short8 aq = ldg8(qp + lr*32 + lq*8);

  // ---- pass 1: partial denominators over this half's 32 chunks
  float rs = 0.f;
  {
    short8 kA0 = ldg8(kb + (size_t)(half*32 + lr)*32 + lq*8);
    short8 kA1 = ldg8(kb + (size_t)(half*32 + 16 + lr)*32 + lq*8);
    short8 kB0, kB1;
#define P1STEP(KC0, KC1, KN0, KN1, NCC) { \
    int nc_ = (NCC); \
    KN0 = ldg8(kb + (size_t)(nc_*32 + lr)*32 + lq*8); \
    KN1 = ldg8(kb + (size_t)(nc_*32 + 16 + lr)*32 + lq*8); \
    f32x4 sa = MFMA16(KC0, aq, z), sb = MFMA16(KC1, aq, z); \
    _Pragma("unroll") for (int r = 0; r < 4; ++r) \
      rs += exp2f(sa[r]*S2LOG) + exp2f(sb[r]*S2LOG); }
    #pragma unroll 1
    for (int s = 0; s < 32; s += 2) {
      P1STEP(kA0, kA1, kB0, kB1, 2*(s+1) + half);
      P1STEP(kB0, kB1, kA0, kA1, (s+2 < 32) ? 2*(s+2) + half : half);
    }
#undef P1STEP
  }
  rs += __shfl_xor(rs, 16, 64);
  rs += __shfl_xor(rs, 32, 64);
  // cross-half reduce via LDS (aliases plds start)
  float* sdl = reinterpret_cast<float*>(plds);
  if (lq == 0) sdl[wave*16 + lr] = rs;
  __syncthreads();
  float lb = -log2f(sdl[head*16 + lr] + sdl[(4+head)*16 + lr]);
  __syncthreads();   // sdl region reused by pass-2 plds writes

  // ---- pass 2: normalized P -> attn_w mean (bf16 LDS) + PV (registers)
  f32x4 acc0 = z, acc1 = z;          // ctx[q=lq*4+r][d=head*32 + dt*16 + lr]
  float* awr = attn_out + (size_t)(b*TT + qt*16)*TT;
  // per-thread mean constants: combined 16x64 tile, 512 threads x f32x2
  int mrow = tid >> 5, mcp = tid & 31;
  const unsigned* pmean = plds + (mcp >> 4)*1152 + mrow*18 + (mcp & 15);
  float* awm = awr + (size_t)mrow*TT + mcp*2;
  unsigned* pw = plds + half*1152 + head*288;

  short8 kA0 = ldg8(kb + (size_t)(half*32 + lr)*32 + lq*8);
  short8 kA1 = ldg8(kb + (size_t)(half*32 + 16 + lr)*32 + lq*8);
  short4v vA00 = ldg4(vb + (size_t)lr*TT + half*32 + lq*4);
  short4v vA01 = ldg4(vb + (size_t)lr*TT + half*32 + 16 + lq*4);
  short4v vA10 = ldg4(vb + (size_t)(16+lr)*TT + half*32 + lq*4);
  short4v vA11 = ldg4(vb + (size_t)(16+lr)*TT + half*32 + 16 + lq*4);
  short8 kB0, kB1; short4v vB00, vB01, vB10, vB11;

#define P2STEP(SI, KC0, KC1, VC00, VC01, VC10, VC11, KN0, KN1, VN00, VN01, VN10, VN11, NCC) { \
    int nc_ = (NCC); \
    KN0 = ldg8(kb + (size_t)(nc_*32 + lr)*32 + lq*8); \
    KN1 = ldg8(kb + (size_t)(nc_*32 + 16 + lr)*32 + lq*8); \
    VN00 = ldg4(vb + (size_t)lr*TT + nc_*32 + lq*4); \
    VN01 = ldg4(vb + (size_t)lr*TT + nc_*32 + 16 + lq*4); \
    VN10 = ldg4(vb + (size_t)(16+lr)*TT + nc_*32 + lq*4); \
    VN11 = ldg4(vb + (size_t)(16+lr)*TT + nc_*32 + 16 + lq*4); \
    f32x4 s0 = MFMA16(KC0, aq, z), s1 = MFMA16(KC1, aq, z); \
    f32x4 p0, p1; \
    _Pragma("unroll") for (int r = 0; r < 4; ++r) { \
      p0[r] = exp2f(fmaf(s0[r], S2LOG, lb)); \
      p1[r] = exp2f(fmaf(s1[r], S2LOG, lb)); } \
    u32x4 ua; \
    ua[0] = cvtpk(p0[0], p0[1]); ua[1] = cvtpk(p0[2], p0[3]); \
    ua[2] = cvtpk(p1[0], p1[1]); ua[3] = cvtpk(p1[2], p1[3]); \
    { unsigned* pd = pw + ((SI)&1)*2304 + lr*18 + 2*lq; \
      *reinterpret_cast<u32x2*>(pd)     = (u32x2){ua[0], ua[1]}; \
      *reinterpret_cast<u32x2*>(pd + 8) = (u32x2){ua[2], ua[3]}; } \
    short8 ap = *reinterpret_cast<short8*>(&ua); \
    short8 vf0, vf1; \
    _Pragma("unroll") for (int j = 0; j < 4; ++j) { \
      vf0[j] = VC00[j]; vf0[4+j] = VC01[j]; \
      vf1[j] = VC10[j]; vf1[4+j] = VC11[j]; } \
    acc0 = MFMA16(ap, vf0, acc0); \
    acc1 = MFMA16(ap, vf1, acc1); \
    __syncthreads(); \
    { const unsigned* pr = pmean + ((SI)&1)*2304; \
      float m0 = 0.f, m1 = 0.f; \
      _Pragma("unroll") for (int h = 0; h < 4; ++h) { \
        unsigned u = pr[h*288]; \
        m0 += __uint_as_float(u << 16); \
        m1 += __uint_as_float(u & 0xffff0000u); } \
      *reinterpret_cast<f32x2*>(awm + (SI)*64) = (f32x2){m0*0.25f, m1*0.25f}; } }

  #pragma unroll 1
  for (int s = 0; s < 32; s += 2) {
    P2STEP(s,   kA0, kA1, vA00, vA01, vA10, vA11,
                kB0, kB1, vB00, vB01, vB10, vB11, 2*(s+1) + half);
    P2STEP(s+1, kB0, kB1, vB00, vB01, vB10, vB11,
                kA0, kA1, vA00, vA01, vA10, vA11, (s+2 < 32) ? 2*(s+2) + half : half);
  }
#undef P2STEP

  // ---- cross-half ctx reduction, then out-proj + residual + LayerNorm
  __syncthreads();   // all mean-reads of plds done before reuse
  size_t rowbase = (size_t)(b*TT) + (size_t)qt*16;
  float* sRed = reinterpret_cast<float*>(plds);   // [half][16 x 132] = 16896B
  {
    float* myR = sRed + half*2112;
    #pragma unroll
    for (int r = 0; r < 4; ++r) {
      int row = lq*4 + r;
      myR[row*132 + head*32 + lr]      = acc0[r];
      myR[row*132 + head*32 + 16 + lr] = acc1[r];
    }
  }
  __syncthreads();
  for (int idx = tid; idx < 2048; idx += 512) {
    int row = idx >> 7, d = idx & 127;
    sRed[row*132 + d] += sRed[2112 + row*132 + d];
  }
  __syncthreads();
  float* sX  = sRed;          // ctx (f32), 16 x 132
  float* sX2 = sRed + 2112;   // x = ctx@Wo^T + bo + lob
  // ctx A-frags from sX (f32 -> bf16 via cvt_pk); same for all waves
  short8 actx[4];
  #pragma unroll
  for (int kt = 0; kt < 4; ++kt) {
    const float* cp = &sX[lr*132 + kt*32 + lq*8];
    f32x4 c0 = *reinterpret_cast<const f32x4*>(cp);
    f32x4 c1 = *reinterpret_cast<const f32x4*>(cp + 4);
    u32x4 u;
    u[0] = cvtpk(c0[0], c0[1]); u[1] = cvtpk(c0[2], c0[3]);
    u[2] = cvtpk(c1[0], c1[1]); u[3] = cvtpk(c1[2], c1[3]);
    actx[kt] = *reinterpret_cast<short8*>(&u);
  }
  // out = ctx @ Wo^T + bo + lob -> sX2 (one N-tile per wave)
  {
    int nt = wave;
    f32x4 acc = z;
    #pragma unroll
    for (int kt = 0; kt < 4; ++kt) {
      short8 bfrag = ldcvt8(Wo + (size_t)(nt*16 + lr)*128 + kt*32 + lq*8);
      acc = MFMA16(actx[kt], bfrag, acc);
    }
    int d = nt*16 + lr;
    float bias = bo[d];
    #pragma unroll
    for (int r = 0; r < 4; ++r) {
      int row = lq*4 + r;
      sX2[row*132 + d] = acc[r] + bias + lobf[(rowbase + row)*128 + d];
    }
  }
  __syncthreads();
  // LayerNorm: 32 threads per row, 4 f32 each
  {
    int row = tid >> 5, j = tid & 31;
    const float* xp = &sX2[row*132 + j*4];
    f32x4 x = *reinterpret_cast<const f32x4*>(xp);
    float sum = x[0] + x[1] + x[2] + x[3];
    float sq  = x[0]*x[0] + x[1]*x[1] + x[2]*x[2] + x[3]*x[3];
    #pragma unroll
    for (int mdx = 1; mdx < 32; mdx <<= 1) {
      sum += __shfl_xor(sum, mdx, 64);
      sq  += __shfl_xor(sq,  mdx, 64);
    }
    float mu = sum * (1.0f/128.0f);
    float rstd = rsqrtf(sq*(1.0f/128.0f) - mu*mu + 1e-5f);
    float* op = outg + (rowbase + row)*128 + j*4;
    f32x4 o;
    #pragma unroll
    for (int e = 0; e < 4; ++e) {
      int d = j*4 + e;
      o[e] = (x[e] - mu)*rstd*gamma[d] + beta[d];
    }
    *reinterpret_cast<f32x4*>(op) = o;
  }
}

extern "C" void kernel_launch(void* const* d_in, const int* in_sizes, int n_in,
                              void* d_out, int out_size, void* d_ws, size_t ws_size,
                              hipStream_t stream) {
  const float* lob    = (const float*)d_in[0];
  const float* hawkes = (const float*)d_in[1];
  const float* Wp     = (const float*)d_in[2];
  const float* bp     = (const float*)d_in[3];
  const float* Win    = (const float*)d_in[4];
  const float* binp   = (const float*)d_in[5];
  const float* Wo     = (const float*)d_in[6];
  const float* bo     = (const float*)d_in[7];
  const float* gamma  = (const float*)d_in[8];
  const float* beta   = (const float*)d_in[9];
  float* outg = (float*)d_out;
  float* attn_out = outg + (size_t)BT*128;   // out (B,T,128) then attn_w (B,T,T)

  char* ws = (char*)d_ws;
  bf16*  qg   = (bf16*)(ws);                                   // 4 MB
  bf16*  kg   = (bf16*)(ws + (size_t)4*1024*1024);             // 4 MB
  bf16*  vtg  = (bf16*)(ws + (size_t)8*1024*1024);             // 4 MB (B,H,32,T)

  proj_kernel<<<BT/32, 256, 0, stream>>>(lob, hawkes, Wp, bp, Win, binp, qg, kg, vtg);
  attn_kernel<<<BB*(TT/16), 512, 0, stream>>>(qg, kg, vtg, attn_out,
                                              lob, Wo, bo, gamma, beta, outg);
}

// Round 12
// 305.745 us; speedup vs baseline: 1.1522x; 1.1522x over previous
//
#include <hip/hip_runtime.h>
#include <hip/hip_bf16.h>
#include <math.h>

#define TT 2048
#define BB 8
#define DD 128
#define HH 4
#define BT (BB*TT)
#define BH (BB*HH)
#define SCALE 0.1767766952966369f
#define S2LOG (SCALE * 1.4426950408889634f)   // scale * log2(e)

typedef __attribute__((ext_vector_type(8))) short short8;
typedef __attribute__((ext_vector_type(4))) short short4v;
typedef __attribute__((ext_vector_type(4))) float f32x4;
typedef __attribute__((ext_vector_type(4))) unsigned u32x4;
typedef __hip_bfloat16 bf16;

#define MFMA16(a,b,c) __builtin_amdgcn_mfma_f32_16x16x32_bf16(a,b,c,0,0,0)

static __device__ inline short8 ldg8(const bf16* p) {
  return *reinterpret_cast<const short8*>(p);
}
static __device__ inline short4v ldg4(const bf16* p) {
  return *reinterpret_cast<const short4v*>(p);
}
static __device__ inline short f2bs(float x) {
  bf16 h = __float2bfloat16(x);
  return *reinterpret_cast<short*>(&h);
}
// single-instruction pack: two f32 -> one u32 holding {bf16(lo) | bf16(hi)<<16}
static __device__ inline unsigned cvtpk(float lo, float hi) {
  unsigned r;
  asm("v_cvt_pk_bf16_f32 %0, %1, %2" : "=v"(r) : "v"(lo), "v"(hi));
  return r;
}
// load 8 contiguous f32 from global, convert to bf16 A/B-fragment
static __device__ inline short8 ldcvt8(const float* p) {
  f32x4 f0 = *reinterpret_cast<const f32x4*>(p);
  f32x4 f1 = *reinterpret_cast<const f32x4*>(p + 4);
  short8 r;
  #pragma unroll
  for (int i = 0; i < 4; ++i) { r[i] = f2bs(f0[i]); r[4+i] = f2bs(f1[i]); }
  return r;
}

// ---------------- Kernel 1: MFMA projections (unchanged) -------------------
__global__ __launch_bounds__(256) void proj_kernel(
    const float* __restrict__ lob, const float* __restrict__ hawkes,
    const float* __restrict__ Wp, const float* __restrict__ bp,
    const float* __restrict__ Win, const float* __restrict__ binp,
    bf16* __restrict__ qg, bf16* __restrict__ kg, bf16* __restrict__ vtg) {
  __shared__ bf16 hT[32*136];   // h tile; reused as q staging after ah read
  __shared__ bf16 sK[32*136];   // k staging
  __shared__ bf16 vT[128*40];   // v^T staging
  int tid = threadIdx.x;
  int wave = tid >> 6, lane = tid & 63;
  int lr = lane & 15, lq = lane >> 4;
  int r0 = blockIdx.x * 32;
  int b  = r0 >> 11, t0 = r0 & 2047;
  f32x4 z = {0.f,0.f,0.f,0.f};

  short8 alob[2][4], ahk[2];
  #pragma unroll
  for (int mt = 0; mt < 2; ++mt) {
    const float* lp = lob + (size_t)(r0 + mt*16 + lr)*128;
    #pragma unroll
    for (int kt = 0; kt < 4; ++kt) alob[mt][kt] = ldcvt8(lp + kt*32 + lq*8);
    ahk[mt] = ldcvt8(hawkes + (size_t)(r0 + mt*16 + lr)*32 + lq*8);
  }

  for (int nt = wave; nt < 8; nt += 4) {
    int cn = nt*16;
    short8 bfrag = ldcvt8(Wp + (size_t)(cn + lr)*32 + lq*8);
    float bias = bp[cn + lr];
    #pragma unroll
    for (int mt = 0; mt < 2; ++mt) {
      f32x4 c = MFMA16(ahk[mt], bfrag, z);
      #pragma unroll
      for (int r = 0; r < 4; ++r)
        hT[(mt*16 + lq*4 + r)*136 + cn + lr] = __float2bfloat16(c[r] + bias);
    }
  }
  __syncthreads();

  short8 ah[2][4];
  #pragma unroll
  for (int mt = 0; mt < 2; ++mt)
    #pragma unroll
    for (int kt = 0; kt < 4; ++kt)
      ah[mt][kt] = *reinterpret_cast<const short8*>(&hT[(mt*16 + lr)*136 + kt*32 + lq*8]);
  __syncthreads();   // hT free -> reuse as q staging

  for (int nt = wave; nt < 24; nt += 4) {
    int which = nt >> 3;
    int c = (nt & 7)*16 + lr;
    const float* wrow = Win + (size_t)(which*128 + c)*128;
    float bias = binp[which*128 + c];
    f32x4 acc0 = z, acc1 = z;
    #pragma unroll
    for (int kt = 0; kt < 4; ++kt) {
      short8 bfrag = ldcvt8(wrow + kt*32 + lq*8);
      if (which == 0) {
        acc0 = MFMA16(alob[0][kt], bfrag, acc0);
        acc1 = MFMA16(alob[1][kt], bfrag, acc1);
      } else {
        acc0 = MFMA16(ah[0][kt], bfrag, acc0);
        acc1 = MFMA16(ah[1][kt], bfrag, acc1);
      }
    }
    #pragma unroll
    for (int mt = 0; mt < 2; ++mt) {
      f32x4 acc = mt ? acc1 : acc0;
      #pragma unroll
      for (int r = 0; r < 4; ++r) {
        int row = mt*16 + lq*4 + r;
        float val = acc[r] + bias;
        if (which == 0)      hT[row*136 + c] = __float2bfloat16(val);
        else if (which == 1) sK[row*136 + c] = __float2bfloat16(val);
        else                 vT[c*40 + row]  = __float2bfloat16(val);
      }
    }
  }
  __syncthreads();

  // q,k writeout: 256 threads x 32B, fully contiguous 4KB per head
  {
    int head = tid >> 6, tt = (tid >> 1) & 31, half = tid & 1;
    const bf16* sq = &hT[tt*136 + head*32 + half*16];
    const bf16* sk = &sK[tt*136 + head*32 + half*16];
    bf16* qdst = qg + ((size_t)(b*HH + head)*TT + t0 + tt)*32 + half*16;
    bf16* kdst = kg + ((size_t)(b*HH + head)*TT + t0 + tt)*32 + half*16;
    *reinterpret_cast<short8*>(qdst)     = *reinterpret_cast<const short8*>(sq);
    *reinterpret_cast<short8*>(qdst + 8) = *reinterpret_cast<const short8*>(sq + 8);
    *reinterpret_cast<short8*>(kdst)     = *reinterpret_cast<const short8*>(sk);
    *reinterpret_cast<short8*>(kdst + 8) = *reinterpret_cast<const short8*>(sk + 8);
  }
  // v writeout: 128 dd-rows x 32 t, coalesced 16B stores
  {
    int dd = tid >> 1, half = tid & 1;
    int bh = b*HH + (dd >> 5);
    short8 s0 = *reinterpret_cast<const short8*>(&vT[dd*40 + half*16]);
    short8 s1 = *reinterpret_cast<const short8*>(&vT[dd*40 + half*16 + 8]);
    bf16* dst = vtg + ((size_t)bh*32 + (dd & 31))*TT + t0 + half*16;
    *reinterpret_cast<short8*>(dst) = s0;
    *reinterpret_cast<short8*>(dst + 8) = s1;
  }
}

// ------- Kernel 2: fused attention + out-proj + residual + LayerNorm -------
// 32 q-rows/block, 512 blocks, 4 waves. K-SPLIT waves: wave w owns chunks
// kc = w + 4i (16 chunks/pass) for ALL 4 heads -> the cross-head attn_w mean
// is an IN-REGISTER sum: ZERO block-wide barriers in the main loops.
// attn_w coalesced via wave-private stride-36 LDS transpose (wave-synchronous,
// no barrier; R4-validated). Register double-buffer prefetch of K AND V
// alternating slots across the unrolled head loop. ctx k-partials reduced
// cross-wave in LDS (2 rounds), then fused out-proj + residual + LN epilogue.
#define KOFF(KC,H) ((size_t)(H)*TT*32 + (size_t)(KC)*1024)
#define VOFF(KC,H) ((size_t)(H)*32*TT + (size_t)(KC)*32)

__global__ __launch_bounds__(256) void attn_kernel(const bf16* __restrict__ qg,
    const bf16* __restrict__ kg, const bf16* __restrict__ vtg,
    float* __restrict__ attn_out, const float* __restrict__ lobf,
    const float* __restrict__ Wo, const float* __restrict__ bo,
    const float* __restrict__ gamma, const float* __restrict__ beta,
    float* __restrict__ outg) {
  // XCD swizzle: 512 blocks = 8 XCDs x 64; each XCD owns one batch b.
  int wgid = (blockIdx.x & 7)*64 + (blockIdx.x >> 3);
  int b = wgid >> 6, qt = wgid & 63;
  int tid = threadIdx.x;
  int wave = tid >> 6, lane = tid & 63;
  int lr = lane & 15, lq = lane >> 4;
  __shared__ float smem[8448];   // 33792 B: Sw staging / sdl / sRed0+sRed1
  const bf16* kb0 = kg + (size_t)(b*HH)*TT*32;
  const bf16* vb0 = vtg + (size_t)(b*HH)*32*TT;
  f32x4 z = {0.f,0.f,0.f,0.f};

  // Q B-frags, all heads: lane holds Q[q = m*16+lr][d = lq*8+j]
  short8 aq[4][2];
  #pragma unroll
  for (int h = 0; h < 4; ++h)
    #pragma unroll
    for (int m = 0; m < 2; ++m)
      aq[h][m] = ldg8(qg + ((size_t)(b*HH + h)*TT + qt*32 + m*16 + lr)*32 + lq*8);

  // ---- pass 1: denominators. lane holds S[q][k = kc*32 + sub*16 + lq*4 + r]
  float rs[4][2] = {{0.f,0.f},{0.f,0.f},{0.f,0.f},{0.f,0.f}};
  short8 kA0, kA1, kB0, kB1;
  kA0 = ldg8(kb0 + KOFF(wave,0) + lr*32 + lq*8);
  kA1 = ldg8(kb0 + KOFF(wave,0) + (16+lr)*32 + lq*8);

#define H1BODY(RS0, RS1, AQ0, AQ1, KC0, KC1, KN0, KN1, NKOFF) { \
    KN0 = ldg8(kb0 + (NKOFF) + lr*32 + lq*8); \
    KN1 = ldg8(kb0 + (NKOFF) + (16+lr)*32 + lq*8); \
    f32x4 s00 = MFMA16(KC0, AQ0, z), s10 = MFMA16(KC1, AQ0, z); \
    f32x4 s01 = MFMA16(KC0, AQ1, z), s11 = MFMA16(KC1, AQ1, z); \
    _Pragma("unroll") for (int r = 0; r < 4; ++r) { \
      RS0 += exp2f(s00[r]*S2LOG) + exp2f(s10[r]*S2LOG); \
      RS1 += exp2f(s01[r]*S2LOG) + exp2f(s11[r]*S2LOG); } }

  #pragma unroll 1
  for (int i = 0; i < 16; ++i) {
    int kc = wave + i*4;
    int kn = (i < 15) ? kc + 4 : wave;
    H1BODY(rs[0][0], rs[0][1], aq[0][0], aq[0][1], kA0, kA1, kB0, kB1, KOFF(kc,1));
    H1BODY(rs[1][0], rs[1][1], aq[1][0], aq[1][1], kB0, kB1, kA0, kA1, KOFF(kc,2));
    H1BODY(rs[2][0], rs[2][1], aq[2][0], aq[2][1], kA0, kA1, kB0, kB1, KOFF(kc,3));
    H1BODY(rs[3][0], rs[3][1], aq[3][0], aq[3][1], kB0, kB1, kA0, kA1, KOFF(kn,0));
  }
#undef H1BODY

  #pragma unroll
  for (int h = 0; h < 4; ++h)
    #pragma unroll
    for (int m = 0; m < 2; ++m) {
      rs[h][m] += __shfl_xor(rs[h][m], 16, 64);
      rs[h][m] += __shfl_xor(rs[h][m], 32, 64);
    }
  if (lq == 0) {
    #pragma unroll
    for (int h = 0; h < 4; ++h)
      #pragma unroll
      for (int m = 0; m < 2; ++m)
        smem[wave*128 + h*32 + m*16 + lr] = rs[h][m];
  }
  __syncthreads();
  float lb[4][2];
  #pragma unroll
  for (int h = 0; h < 4; ++h)
    #pragma unroll
    for (int m = 0; m < 2; ++m)
      lb[h][m] = -log2f(smem[0*128 + h*32 + m*16 + lr] + smem[1*128 + h*32 + m*16 + lr]
                      + smem[2*128 + h*32 + m*16 + lr] + smem[3*128 + h*32 + m*16 + lr]);
  __syncthreads();   // sdl region reused as wave-private Sw staging

  // ---- pass 2: normalized P -> in-register head-mean + PV. No barriers.
  f32x4 acc[4][2][2];   // [h][m][dt]: q = m*16+lq*4+r, d = h*32+dt*16+lr
  #pragma unroll
  for (int h = 0; h < 4; ++h)
    #pragma unroll
    for (int m = 0; m < 2; ++m)
      #pragma unroll
      for (int dt = 0; dt < 2; ++dt) acc[h][m][dt] = z;
  f32x4 aw00 = z, aw01 = z, aw10 = z, aw11 = z;   // [m][sub]
  float* Sw = smem + wave*1152;                    // 32 x 36 wave-private
  float* awr = attn_out + (size_t)(b*TT + qt*32)*TT;

  short4v vA00, vA01, vA10, vA11, vB00, vB01, vB10, vB11;
  kA0 = ldg8(kb0 + KOFF(wave,0) + lr*32 + lq*8);
  kA1 = ldg8(kb0 + KOFF(wave,0) + (16+lr)*32 + lq*8);
  vA00 = ldg4(vb0 + VOFF(wave,0) + (size_t)lr*TT + lq*4);
  vA01 = ldg4(vb0 + VOFF(wave,0) + (size_t)lr*TT + 16 + lq*4);
  vA10 = ldg4(vb0 + VOFF(wave,0) + (size_t)(16+lr)*TT + lq*4);
  vA11 = ldg4(vb0 + VOFF(wave,0) + (size_t)(16+lr)*TT + 16 + lq*4);

#define HBODY(ACCH, LB0, LB1, AQ0, AQ1, KC0, KC1, VC00, VC01, VC10, VC11, \
              KN0, KN1, VN00, VN01, VN10, VN11, NKOFF, NVOFF) { \
    KN0 = ldg8(kb0 + (NKOFF) + lr*32 + lq*8); \
    KN1 = ldg8(kb0 + (NKOFF) + (16+lr)*32 + lq*8); \
    VN00 = ldg4(vb0 + (NVOFF) + (size_t)lr*TT + lq*4); \
    VN01 = ldg4(vb0 + (NVOFF) + (size_t)lr*TT + 16 + lq*4); \
    VN10 = ldg4(vb0 + (NVOFF) + (size_t)(16+lr)*TT + lq*4); \
    VN11 = ldg4(vb0 + (NVOFF) + (size_t)(16+lr)*TT + 16 + lq*4); \
    f32x4 s00 = MFMA16(KC0, AQ0, z), s10 = MFMA16(KC1, AQ0, z); \
    f32x4 s01 = MFMA16(KC0, AQ1, z), s11 = MFMA16(KC1, AQ1, z); \
    f32x4 p00, p10, p01, p11; \
    _Pragma("unroll") for (int r = 0; r < 4; ++r) { \
      p00[r] = exp2f(fmaf(s00[r], S2LOG, LB0)); \
      p10[r] = exp2f(fmaf(s10[r], S2LOG, LB0)); \
      p01[r] = exp2f(fmaf(s01[r], S2LOG, LB1)); \
      p11[r] = exp2f(fmaf(s11[r], S2LOG, LB1)); } \
    aw00 += p00; aw01 += p10; aw10 += p01; aw11 += p11; \
    u32x4 ua_, ub_; \
    ua_[0] = cvtpk(p00[0], p00[1]); ua_[1] = cvtpk(p00[2], p00[3]); \
    ua_[2] = cvtpk(p10[0], p10[1]); ua_[3] = cvtpk(p10[2], p10[3]); \
    ub_[0] = cvtpk(p01[0], p01[1]); ub_[1] = cvtpk(p01[2], p01[3]); \
    ub_[2] = cvtpk(p11[0], p11[1]); ub_[3] = cvtpk(p11[2], p11[3]); \
    short8 ap0 = *reinterpret_cast<short8*>(&ua_); \
    short8 ap1 = *reinterpret_cast<short8*>(&ub_); \
    short8 vf0, vf1; \
    _Pragma("unroll") for (int j = 0; j < 4; ++j) { \
      vf0[j] = VC00[j]; vf0[4+j] = VC01[j]; \
      vf1[j] = VC10[j]; vf1[4+j] = VC11[j]; } \
    ACCH[0][0] = MFMA16(ap0, vf0, ACCH[0][0]); \
    ACCH[0][1] = MFMA16(ap0, vf1, ACCH[0][1]); \
    ACCH[1][0] = MFMA16(ap1, vf0, ACCH[1][0]); \
    ACCH[1][1] = MFMA16(ap1, vf1, ACCH[1][1]); }

  #pragma unroll 1
  for (int i = 0; i < 16; ++i) {
    int kc = wave + i*4;
    int kn = (i < 15) ? kc + 4 : wave;
    HBODY(acc[0], lb[0][0], lb[0][1], aq[0][0], aq[0][1],
          kA0, kA1, vA00, vA01, vA10, vA11,
          kB0, kB1, vB00, vB01, vB10, vB11, KOFF(kc,1), VOFF(kc,1));
    HBODY(acc[1], lb[1][0], lb[1][1], aq[1][0], aq[1][1],
          kB0, kB1, vB00, vB01, vB10, vB11,
          kA0, kA1, vA00, vA01, vA10, vA11, KOFF(kc,2), VOFF(kc,2));
    HBODY(acc[2], lb[2][0], lb[2][1], aq[2][0], aq[2][1],
          kA0, kA1, vA00, vA01, vA10, vA11,
          kB0, kB1, vB00, vB01, vB10, vB11, KOFF(kc,3), VOFF(kc,3));
    HBODY(acc[3], lb[3][0], lb[3][1], aq[3][0], aq[3][1],
          kB0, kB1, vB00, vB01, vB10, vB11,
          kA0, kA1, vA00, vA01, vA10, vA11, KOFF(kn,0), VOFF(kn,0));
    // attn_w: wave-private LDS transpose (no barrier), coalesced f32x4 stores
    *reinterpret_cast<f32x4*>(&Sw[lr*36 + lq*4])           = aw00 * 0.25f;
    *reinterpret_cast<f32x4*>(&Sw[lr*36 + 16 + lq*4])      = aw01 * 0.25f;
    *reinterpret_cast<f32x4*>(&Sw[(16+lr)*36 + lq*4])      = aw10 * 0.25f;
    *reinterpret_cast<f32x4*>(&Sw[(16+lr)*36 + 16 + lq*4]) = aw11 * 0.25f;
    #pragma unroll
    for (int g = 0; g < 4; ++g) {
      int row = g*8 + (lane >> 3), col = (lane & 7)*4;
      *reinterpret_cast<f32x4*>(awr + (size_t)row*TT + kc*32 + col) =
          *reinterpret_cast<const f32x4*>(&Sw[row*36 + col]);
    }
    aw00 = z; aw01 = z; aw10 = z; aw11 = z;
  }
#undef HBODY

  // ---- cross-wave ctx reduction (k-partials), 2 rounds
  __syncthreads();
  size_t rowbase = (size_t)(b*TT) + (size_t)qt*32;
  float* sRed0 = smem;
  float* sRed1 = smem + 4224;
  if (wave < 2) {
    float* myR = (wave == 0) ? sRed0 : sRed1;
    #pragma unroll
    for (int h = 0; h < 4; ++h)
      #pragma unroll
      for (int m = 0; m < 2; ++m)
        #pragma unroll
        for (int dt = 0; dt < 2; ++dt)
          #pragma unroll
          for (int r = 0; r < 4; ++r)
            myR[(m*16 + lq*4 + r)*132 + h*32 + dt*16 + lr] = acc[h][m][dt][r];
  }
  __syncthreads();
  if (wave >= 2) {
    float* myR = (wave == 2) ? sRed0 : sRed1;
    #pragma unroll
    for (int h = 0; h < 4; ++h)
      #pragma unroll
      for (int m = 0; m < 2; ++m)
        #pragma unroll
        for (int dt = 0; dt < 2; ++dt)
          #pragma unroll
          for (int r = 0; r < 4; ++r)
            myR[(m*16 + lq*4 + r)*132 + h*32 + dt*16 + lr] += acc[h][m][dt][r];
  }
  __syncthreads();
  // ctx A-frags = sRed0 + sRed1 (f32 -> bf16 via cvt_pk); same for all waves
  short8 actx[2][4];
  #pragma unroll
  for (int mt = 0; mt < 2; ++mt)
    #pragma unroll
    for (int kt = 0; kt < 4; ++kt) {
      int off = (mt*16 + lr)*132 + kt*32 + lq*8;
      f32x4 c0 = *reinterpret_cast<const f32x4*>(&sRed0[off])
               + *reinterpret_cast<const f32x4*>(&sRed1[off]);
      f32x4 c1 = *reinterpret_cast<const f32x4*>(&sRed0[off + 4])
               + *reinterpret_cast<const f32x4*>(&sRed1[off + 4]);
      u32x4 u;
      u[0] = cvtpk(c0[0], c0[1]); u[1] = cvtpk(c0[2], c0[3]);
      u[2] = cvtpk(c1[0], c1[1]); u[3] = cvtpk(c1[2], c1[3]);
      actx[mt][kt] = *reinterpret_cast<short8*>(&u);
    }
  __syncthreads();
  // out = ctx @ Wo^T + bo + lob -> sX2 (2 N-tiles per wave)
  float* sX2 = smem;   // reuse sRed0 region
  #pragma unroll
  for (int t = 0; t < 2; ++t) {
    int nt = wave + t*4;
    f32x4 a0 = z, a1 = z;
    #pragma unroll
    for (int kt = 0; kt < 4; ++kt) {
      short8 bfrag = ldcvt8(Wo + (size_t)(nt*16 + lr)*128 + kt*32 + lq*8);
      a0 = MFMA16(actx[0][kt], bfrag, a0);
      a1 = MFMA16(actx[1][kt], bfrag, a1);
    }
    int d = nt*16 + lr;
    float bias = bo[d];
    #pragma unroll
    for (int m = 0; m < 2; ++m) {
      f32x4 a = m ? a1 : a0;
      #pragma unroll
      for (int r = 0; r < 4; ++r) {
        int row = m*16 + lq*4 + r;
        sX2[row*132 + d] = a[r] + bias + lobf[(rowbase + row)*128 + d];
      }
    }
  }
  __syncthreads();
  // LayerNorm: 8 threads per row, 16 f32 each (R7-validated)
  {
    int row = tid >> 3, j = tid & 7;
    const float* xp = &sX2[row*132 + j*16];
    f32x4 x[4];
    #pragma unroll
    for (int v = 0; v < 4; ++v) x[v] = *reinterpret_cast<const f32x4*>(xp + v*4);
    float sum = 0.f, sq = 0.f;
    #pragma unroll
    for (int v = 0; v < 4; ++v)
      #pragma unroll
      for (int e = 0; e < 4; ++e) { sum += x[v][e]; sq += x[v][e]*x[v][e]; }
    #pragma unroll
    for (int mdx = 1; mdx < 8; mdx <<= 1) {
      sum += __shfl_xor(sum, mdx, 64);
      sq  += __shfl_xor(sq,  mdx, 64);
    }
    float mu = sum * (1.0f/128.0f);
    float rstd = rsqrtf(sq*(1.0f/128.0f) - mu*mu + 1e-5f);
    float* op = outg + (rowbase + row)*128 + j*16;
    #pragma unroll
    for (int v = 0; v < 4; ++v) {
      f32x4 o;
      #pragma unroll
      for (int e = 0; e < 4; ++e) {
        int d = j*16 + v*4 + e;
        o[e] = (x[v][e] - mu)*rstd*gamma[d] + beta[d];
      }
      *reinterpret_cast<f32x4*>(op + v*4) = o;
    }
  }
}

extern "C" void kernel_launch(void* const* d_in, const int* in_sizes, int n_in,
                              void* d_out, int out_size, void* d_ws, size_t ws_size,
                              hipStream_t stream) {
  const float* lob    = (const float*)d_in[0];
  const float* hawkes = (const float*)d_in[1];
  const float* Wp     = (const float*)d_in[2];
  const float* bp     = (const float*)d_in[3];
  const float* Win    = (const float*)d_in[4];
  const float* binp   = (const float*)d_in[5];
  const float* Wo     = (const float*)d_in[6];
  const float* bo     = (const float*)d_in[7];
  const float* gamma  = (const float*)d_in[8];
  const float* beta   = (const float*)d_in[9];
  float* outg = (float*)d_out;
  float* attn_out = outg + (size_t)BT*128;   // out (B,T,128) then attn_w (B,T,T)

  char* ws = (char*)d_ws;
  bf16*  qg   = (bf16*)(ws);                                   // 4 MB
  bf16*  kg   = (bf16*)(ws + (size_t)4*1024*1024);             // 4 MB
  bf16*  vtg  = (bf16*)(ws + (size_t)8*1024*1024);             // 4 MB (B,H,32,T)

  proj_kernel<<<BT/32, 256, 0, stream>>>(lob, hawkes, Wp, bp, Win, binp, qg, kg, vtg);
  attn_kernel<<<BB*(TT/32), 256, 0, stream>>>(qg, kg, vtg, attn_out,
                                              lob, Wo, bo, gamma, beta, outg);
}

// Round 14
// 267.208 us; speedup vs baseline: 1.3183x; 1.1442x over previous
//
#include <hip/hip_runtime.h>
#include <hip/hip_bf16.h>
#include <math.h>

#define TT 2048
#define BB 8
#define DD 128
#define HH 4
#define BT (BB*TT)
#define BH (BB*HH)
#define SCALE 0.1767766952966369f
#define S2LOG (SCALE * 1.4426950408889634f)   // scale * log2(e)

typedef __attribute__((ext_vector_type(8))) short short8;
typedef __attribute__((ext_vector_type(4))) short short4v;
typedef __attribute__((ext_vector_type(4))) float f32x4;
typedef __attribute__((ext_vector_type(4))) unsigned u32x4;
typedef __hip_bfloat16 bf16;

#define MFMA16(a,b,c) __builtin_amdgcn_mfma_f32_16x16x32_bf16(a,b,c,0,0,0)

static __device__ inline short8 ldg8(const bf16* p) {
  return *reinterpret_cast<const short8*>(p);
}
static __device__ inline short4v ldg4(const bf16* p) {
  return *reinterpret_cast<const short4v*>(p);
}
static __device__ inline short f2bs(float x) {
  bf16 h = __float2bfloat16(x);
  return *reinterpret_cast<short*>(&h);
}
// single-instruction pack: two f32 -> one u32 holding {bf16(lo) | bf16(hi)<<16}
static __device__ inline unsigned cvtpk(float lo, float hi) {
  unsigned r;
  asm("v_cvt_pk_bf16_f32 %0, %1, %2" : "=v"(r) : "v"(lo), "v"(hi));
  return r;
}
// load 8 contiguous f32 from global, convert to bf16 A/B-fragment
static __device__ inline short8 ldcvt8(const float* p) {
  f32x4 f0 = *reinterpret_cast<const f32x4*>(p);
  f32x4 f1 = *reinterpret_cast<const f32x4*>(p + 4);
  short8 r;
  #pragma unroll
  for (int i = 0; i < 4; ++i) { r[i] = f2bs(f0[i]); r[4+i] = f2bs(f1[i]); }
  return r;
}

// -------- Kernel 0: one-time weight conversion f32 -> bf16 -----------------
// Kills the per-block redundant conversion (512x for Win) and turns the
// 64-way-scattered f32 weight reads in proj/attn-epilogue into contiguous
// 64B-per-row bf16 reads. Layout: [0,4096) Wp | [4096,53248) Win |
// [53248,69632) Wo (row-major, original shapes).
__global__ __launch_bounds__(256) void prep_kernel(
    const float* __restrict__ Wp, const float* __restrict__ Win,
    const float* __restrict__ Wo, bf16* __restrict__ wb) {
  int i = (blockIdx.x*256 + threadIdx.x)*4;
  const float* src; int off;
  if (i < 4096)       { src = Wp;  off = i; }
  else if (i < 53248) { src = Win; off = i - 4096; }
  else                { src = Wo;  off = i - 53248; }
  f32x4 v = *reinterpret_cast<const f32x4*>(src + off);
  short4v o;
  #pragma unroll
  for (int j = 0; j < 4; ++j) o[j] = f2bs(v[j]);
  *reinterpret_cast<short4v*>(wb + i) = o;
}

// ---------------- Kernel 1: MFMA projections (bf16 weights) ----------------
__global__ __launch_bounds__(256) void proj_kernel(
    const float* __restrict__ lob, const float* __restrict__ hawkes,
    const bf16* __restrict__ wb, const float* __restrict__ bp,
    const float* __restrict__ binp,
    bf16* __restrict__ qg, bf16* __restrict__ kg, bf16* __restrict__ vtg) {
  const bf16* wpb  = wb;          // 128 x 32
  const bf16* winb = wb + 4096;   // 384 x 128
  __shared__ bf16 hT[32*136];   // h tile; reused as q staging after ah read
  __shared__ bf16 sK[32*136];   // k staging
  __shared__ bf16 vT[128*40];   // v^T staging
  int tid = threadIdx.x;
  int wave = tid >> 6, lane = tid & 63;
  int lr = lane & 15, lq = lane >> 4;
  int r0 = blockIdx.x * 32;
  int b  = r0 >> 11, t0 = r0 & 2047;
  f32x4 z = {0.f,0.f,0.f,0.f};

  short8 alob[2][4], ahk[2];
  #pragma unroll
  for (int mt = 0; mt < 2; ++mt) {
    const float* lp = lob + (size_t)(r0 + mt*16 + lr)*128;
    #pragma unroll
    for (int kt = 0; kt < 4; ++kt) alob[mt][kt] = ldcvt8(lp + kt*32 + lq*8);
    ahk[mt] = ldcvt8(hawkes + (size_t)(r0 + mt*16 + lr)*32 + lq*8);
  }

  for (int nt = wave; nt < 8; nt += 4) {
    int cn = nt*16;
    short8 bfrag = ldg8(wpb + (size_t)(cn + lr)*32 + lq*8);
    float bias = bp[cn + lr];
    #pragma unroll
    for (int mt = 0; mt < 2; ++mt) {
      f32x4 c = MFMA16(ahk[mt], bfrag, z);
      #pragma unroll
      for (int r = 0; r < 4; ++r)
        hT[(mt*16 + lq*4 + r)*136 + cn + lr] = __float2bfloat16(c[r] + bias);
    }
  }
  __syncthreads();

  short8 ah[2][4];
  #pragma unroll
  for (int mt = 0; mt < 2; ++mt)
    #pragma unroll
    for (int kt = 0; kt < 4; ++kt)
      ah[mt][kt] = *reinterpret_cast<const short8*>(&hT[(mt*16 + lr)*136 + kt*32 + lq*8]);
  __syncthreads();   // hT free -> reuse as q staging

  for (int nt = wave; nt < 24; nt += 4) {
    int which = nt >> 3;
    int c = (nt & 7)*16 + lr;
    const bf16* wrow = winb + (size_t)(which*128 + c)*128;
    float bias = binp[which*128 + c];
    f32x4 acc0 = z, acc1 = z;
    #pragma unroll
    for (int kt = 0; kt < 4; ++kt) {
      short8 bfrag = ldg8(wrow + kt*32 + lq*8);
      if (which == 0) {
        acc0 = MFMA16(alob[0][kt], bfrag, acc0);
        acc1 = MFMA16(alob[1][kt], bfrag, acc1);
      } else {
        acc0 = MFMA16(ah[0][kt], bfrag, acc0);
        acc1 = MFMA16(ah[1][kt], bfrag, acc1);
      }
    }
    #pragma unroll
    for (int mt = 0; mt < 2; ++mt) {
      f32x4 acc = mt ? acc1 : acc0;
      #pragma unroll
      for (int r = 0; r < 4; ++r) {
        int row = mt*16 + lq*4 + r;
        float val = acc[r] + bias;
        if (which == 0)      hT[row*136 + c] = __float2bfloat16(val);
        else if (which == 1) sK[row*136 + c] = __float2bfloat16(val);
        else                 vT[c*40 + row]  = __float2bfloat16(val);
      }
    }
  }
  __syncthreads();

  // q,k writeout: 256 threads x 32B, fully contiguous 4KB per head
  {
    int head = tid >> 6, tt = (tid >> 1) & 31, half = tid & 1;
    const bf16* sq = &hT[tt*136 + head*32 + half*16];
    const bf16* sk = &sK[tt*136 + head*32 + half*16];
    bf16* qdst = qg + ((size_t)(b*HH + head)*TT + t0 + tt)*32 + half*16;
    bf16* kdst = kg + ((size_t)(b*HH + head)*TT + t0 + tt)*32 + half*16;
    *reinterpret_cast<short8*>(qdst)     = *reinterpret_cast<const short8*>(sq);
    *reinterpret_cast<short8*>(qdst + 8) = *reinterpret_cast<const short8*>(sq + 8);
    *reinterpret_cast<short8*>(kdst)     = *reinterpret_cast<const short8*>(sk);
    *reinterpret_cast<short8*>(kdst + 8) = *reinterpret_cast<const short8*>(sk + 8);
  }
  // v writeout: 128 dd-rows x 32 t, coalesced 16B stores
  {
    int dd = tid >> 1, half = tid & 1;
    int bh = b*HH + (dd >> 5);
    short8 s0 = *reinterpret_cast<const short8*>(&vT[dd*40 + half*16]);
    short8 s1 = *reinterpret_cast<const short8*>(&vT[dd*40 + half*16 + 8]);
    bf16* dst = vtg + ((size_t)bh*32 + (dd & 31))*TT + t0 + half*16;
    *reinterpret_cast<short8*>(dst) = s0;
    *reinterpret_cast<short8*>(dst + 8) = s1;
  }
}

// ------- Kernel 2: fused attention + out-proj + residual + LayerNorm -------
// EXACTLY R8's measured-best kernel (8 waves = head x k-parity-half, 32
// q-rows, register prefetch, fused epilogue), with the epilogue's Wo read
// switched to preconverted bf16 (ldg8 instead of scattered f32 ldcvt8).
__global__ __launch_bounds__(512) void attn_kernel(const bf16* __restrict__ qg,
    const bf16* __restrict__ kg, const bf16* __restrict__ vtg,
    float* __restrict__ attn_out, const float* __restrict__ lobf,
    const bf16* __restrict__ wb, const float* __restrict__ bo,
    const float* __restrict__ gamma, const float* __restrict__ beta,
    float* __restrict__ outg) {
  const bf16* wob = wb + 53248;   // 128 x 128 bf16
  // XCD swizzle: 512 blocks = 8 XCDs x 64; each XCD owns one batch b.
  int wgid = (blockIdx.x & 7)*64 + (blockIdx.x >> 3);
  int b = wgid >> 6, qt = wgid & 63;
  int tid = threadIdx.x;
  int wave = tid >> 6, lane = tid & 63;
  int head = wave & 3, half = wave >> 2;
  int lr = lane & 15, lq = lane >> 4;
  int bh = b*HH + head;
  __shared__ float plds[2][4][32*36];   // [half][head][32x36] = 36864 B
  const bf16* qp = qg + ((size_t)bh*TT + (size_t)qt*32)*32;
  const bf16* kb = kg + (size_t)bh*TT*32;
  const bf16* vb = vtg + (size_t)bh*32*TT;
  f32x4 z = {0.f,0.f,0.f,0.f};

  // Q B-frags: lane holds Q[q=m*16+lr][d=lq*8+j]
  short8 aq0 = ldg8(qp + lr*32 + lq*8);
  short8 aq1 = ldg8(qp + (16+lr)*32 + lq*8);

  // ---- pass 1: partial denominators over this half's 32 chunks (parity half)
  float rs0 = 0.f, rs1 = 0.f;
  {
    short8 kA0 = ldg8(kb + (size_t)(half*32 + lr)*32 + lq*8);
    short8 kA1 = ldg8(kb + (size_t)(half*32 + 16 + lr)*32 + lq*8);
    short8 kB0, kB1;
#define P1STEP(KC0, KC1, KN0, KN1, NCC) { \
    int nc_ = (NCC); \
    KN0 = ldg8(kb + (size_t)(nc_*32 + lr)*32 + lq*8); \
    KN1 = ldg8(kb + (size_t)(nc_*32 + 16 + lr)*32 + lq*8); \
    f32x4 sa0 = MFMA16(KC0, aq0, z), sb0 = MFMA16(KC1, aq0, z); \
    f32x4 sa1 = MFMA16(KC0, aq1, z), sb1 = MFMA16(KC1, aq1, z); \
    _Pragma("unroll") for (int r = 0; r < 4; ++r) { \
      rs0 += exp2f(sa0[r]*S2LOG) + exp2f(sb0[r]*S2LOG); \
      rs1 += exp2f(sa1[r]*S2LOG) + exp2f(sb1[r]*S2LOG); } }
    #pragma unroll 1
    for (int i = 0; i < 32; i += 2) {
      P1STEP(kA0, kA1, kB0, kB1, 2*(i+1) + half);
      P1STEP(kB0, kB1, kA0, kA1, (i+2 < 32) ? 2*(i+2) + half : half);
    }
#undef P1STEP
  }
  rs0 += __shfl_xor(rs0, 16, 64); rs0 += __shfl_xor(rs0, 32, 64);
  rs1 += __shfl_xor(rs1, 16, 64); rs1 += __shfl_xor(rs1, 32, 64);
  // cross-half reduce via LDS (sdl aliases plds[0][0][0:256])
  float* sdl = &plds[0][0][0];
  if (lq == 0) { sdl[wave*32 + lr] = rs0; sdl[wave*32 + 16 + lr] = rs1; }
  __syncthreads();
  float lb0 = -log2f(sdl[head*32 + lr]      + sdl[(4+head)*32 + lr]);
  float lb1 = -log2f(sdl[head*32 + 16 + lr] + sdl[(4+head)*32 + 16 + lr]);
  __syncthreads();   // sdl region reused by pass-2 plds writes

  // ---- pass 2: normalized P -> attn_w mean (via plds) + PV (registers)
  f32x4 acc00 = z, acc01 = z, acc10 = z, acc11 = z;  // [m][dt], this half
  float* awr = attn_out + (size_t)(b*TT + qt*32)*TT;
  int mloc = tid & 255;
  int mq = mloc >> 3, mk = (mloc & 7)*4;   // mean mapping: 256 thr per half

  short8 kA0 = ldg8(kb + (size_t)(half*32 + lr)*32 + lq*8);
  short8 kA1 = ldg8(kb + (size_t)(half*32 + 16 + lr)*32 + lq*8);
  short4v vA00 = ldg4(vb + (size_t)lr*TT + half*32 + lq*4);
  short4v vA01 = ldg4(vb + (size_t)lr*TT + half*32 + 16 + lq*4);
  short4v vA10 = ldg4(vb + (size_t)(16+lr)*TT + half*32 + lq*4);
  short4v vA11 = ldg4(vb + (size_t)(16+lr)*TT + half*32 + 16 + lq*4);
  short8 kB0, kB1; short4v vB00, vB01, vB10, vB11;

#define P2STEP(SI, KC0, KC1, VC00, VC01, VC10, VC11, KN0, KN1, VN00, VN01, VN10, VN11, NCC) { \
    int kc_ = (SI); int nc_ = (NCC); \
    KN0 = ldg8(kb + (size_t)(nc_*32 + lr)*32 + lq*8); \
    KN1 = ldg8(kb + (size_t)(nc_*32 + 16 + lr)*32 + lq*8); \
    VN00 = ldg4(vb + (size_t)lr*TT + nc_*32 + lq*4); \
    VN01 = ldg4(vb + (size_t)lr*TT + nc_*32 + 16 + lq*4); \
    VN10 = ldg4(vb + (size_t)(16+lr)*TT + nc_*32 + lq*4); \
    VN11 = ldg4(vb + (size_t)(16+lr)*TT + nc_*32 + 16 + lq*4); \
    f32x4 s00 = MFMA16(KC0, aq0, z), s10 = MFMA16(KC1, aq0, z); \
    f32x4 s01 = MFMA16(KC0, aq1, z), s11 = MFMA16(KC1, aq1, z); \
    f32x4 p00, p10, p01, p11; \
    _Pragma("unroll") for (int r = 0; r < 4; ++r) { \
      p00[r] = exp2f(fmaf(s00[r], S2LOG, lb0)); \
      p10[r] = exp2f(fmaf(s10[r], S2LOG, lb0)); \
      p01[r] = exp2f(fmaf(s01[r], S2LOG, lb1)); \
      p11[r] = exp2f(fmaf(s11[r], S2LOG, lb1)); } \
    { float* pw = &plds[half][head][0]; \
      *reinterpret_cast<f32x4*>(pw + lr*36 + lq*4)           = p00; \
      *reinterpret_cast<f32x4*>(pw + lr*36 + 16 + lq*4)      = p10; \
      *reinterpret_cast<f32x4*>(pw + (16+lr)*36 + lq*4)      = p01; \
      *reinterpret_cast<f32x4*>(pw + (16+lr)*36 + 16 + lq*4) = p11; } \
    u32x4 ua_, ub_; \
    ua_[0] = cvtpk(p00[0], p00[1]); ua_[1] = cvtpk(p00[2], p00[3]); \
    ua_[2] = cvtpk(p10[0], p10[1]); ua_[3] = cvtpk(p10[2], p10[3]); \
    ub_[0] = cvtpk(p01[0], p01[1]); ub_[1] = cvtpk(p01[2], p01[3]); \
    ub_[2] = cvtpk(p11[0], p11[1]); ub_[3] = cvtpk(p11[2], p11[3]); \
    short8 ap0 = *reinterpret_cast<short8*>(&ua_); \
    short8 ap1 = *reinterpret_cast<short8*>(&ub_); \
    __syncthreads(); \
    { const float* pr = &plds[half][0][0]; \
      f32x4 mv = *reinterpret_cast<const f32x4*>(pr + mq*36 + mk); \
      mv = mv + *reinterpret_cast<const f32x4*>(pr + 1152 + mq*36 + mk); \
      mv = mv + *reinterpret_cast<const f32x4*>(pr + 2304 + mq*36 + mk); \
      mv = mv + *reinterpret_cast<const f32x4*>(pr + 3456 + mq*36 + mk); \
      *reinterpret_cast<f32x4*>(awr + (size_t)mq*TT + kc_*32 + mk) = mv * 0.25f; } \
    short8 vf0, vf1; \
    _Pragma("unroll") for (int j = 0; j < 4; ++j) { \
      vf0[j] = VC00[j]; vf0[4+j] = VC01[j]; \
      vf1[j] = VC10[j]; vf1[4+j] = VC11[j]; } \
    acc00 = MFMA16(ap0, vf0, acc00); acc01 = MFMA16(ap0, vf1, acc01); \
    acc10 = MFMA16(ap1, vf0, acc10); acc11 = MFMA16(ap1, vf1, acc11); \
    __syncthreads(); }

  #pragma unroll 1
  for (int i = 0; i < 32; i += 2) {
    P2STEP(2*i + half, kA0, kA1, vA00, vA01, vA10, vA11,
           kB0, kB1, vB00, vB01, vB10, vB11, 2*(i+1) + half);
    P2STEP(2*(i+1) + half, kB0, kB1, vB00, vB01, vB10, vB11,
           kA0, kA1, vA00, vA01, vA10, vA11, (i+2 < 32) ? 2*(i+2) + half : half);
  }
#undef P2STEP

  // ---- cross-half ctx reduction, then out-proj + residual + LayerNorm
  size_t rowbase = (size_t)(b*TT) + (size_t)qt*32;
  float* sRed = &plds[0][0][0];   // [half][32 x 132] = 8448 floats (of 9216)
  {
    float* myR = sRed + half*4224;
    #pragma unroll
    for (int m = 0; m < 2; ++m) {
      f32x4 a0 = m ? acc10 : acc00;
      f32x4 a1 = m ? acc11 : acc01;
      #pragma unroll
      for (int r = 0; r < 4; ++r) {
        int row = m*16 + lq*4 + r;
        myR[row*132 + head*32 + lr]      = a0[r];
        myR[row*132 + head*32 + 16 + lr] = a1[r];
      }
    }
  }
  __syncthreads();
  for (int idx = tid; idx < 4096; idx += 512) {
    int row = idx >> 7, d = idx & 127;
    sRed[row*132 + d] += sRed[4224 + row*132 + d];
  }
  __syncthreads();
  float* sX  = sRed;          // ctx (f32), 32 x 132
  float* sX2 = sRed + 4224;   // x = ctx@Wo^T + bo + lob
  // ctx A-frags from sX (f32 -> bf16 via cvt_pk); same for all waves
  short8 actx[2][4];
  #pragma unroll
  for (int mt = 0; mt < 2; ++mt)
    #pragma unroll
    for (int kt = 0; kt < 4; ++kt) {
      const float* cp = &sX[(mt*16 + lr)*132 + kt*32 + lq*8];
      f32x4 c0 = *reinterpret_cast<const f32x4*>(cp);
      f32x4 c1 = *reinterpret_cast<const f32x4*>(cp + 4);
      u32x4 u;
      u[0] = cvtpk(c0[0], c0[1]); u[1] = cvtpk(c0[2], c0[3]);
      u[2] = cvtpk(c1[0], c1[1]); u[3] = cvtpk(c1[2], c1[3]);
      actx[mt][kt] = *reinterpret_cast<short8*>(&u);
    }
  // out = ctx @ Wo^T + bo + lob -> sX2 (one N-tile per wave)
  {
    int nt = wave;
    f32x4 acc0 = z, acc1 = z;
    #pragma unroll
    for (int kt = 0; kt < 4; ++kt) {
      short8 bfrag = ldg8(wob + (size_t)(nt*16 + lr)*128 + kt*32 + lq*8);
      acc0 = MFMA16(actx[0][kt], bfrag, acc0);
      acc1 = MFMA16(actx[1][kt], bfrag, acc1);
    }
    int d = nt*16 + lr;
    float bias = bo[d];
    #pragma unroll
    for (int mt = 0; mt < 2; ++mt) {
      f32x4 acc = mt ? acc1 : acc0;
      #pragma unroll
      for (int r = 0; r < 4; ++r) {
        int row = mt*16 + lq*4 + r;
        sX2[row*132 + d] = acc[r] + bias + lobf[(rowbase + row)*128 + d];
      }
    }
  }
  __syncthreads();
  // LayerNorm: 16 threads per row, 8 f32 each
  {
    int row = tid >> 4, j = tid & 15;
    const float* xp = &sX2[row*132 + j*8];
    f32x4 x0 = *reinterpret_cast<const f32x4*>(xp);
    f32x4 x1 = *reinterpret_cast<const f32x4*>(xp + 4);
    float sum = 0.f, sq = 0.f;
    #pragma unroll
    for (int e = 0; e < 4; ++e) {
      sum += x0[e] + x1[e];
      sq  += x0[e]*x0[e] + x1[e]*x1[e];
    }
    #pragma unroll
    for (int mdx = 1; mdx < 16; mdx <<= 1) {
      sum += __shfl_xor(sum, mdx, 64);
      sq  += __shfl_xor(sq,  mdx, 64);
    }
    float mu = sum * (1.0f/128.0f);
    float rstd = rsqrtf(sq*(1.0f/128.0f) - mu*mu + 1e-5f);
    float* op = outg + (rowbase + row)*128 + j*8;
    f32x4 o0, o1;
    #pragma unroll
    for (int e = 0; e < 4; ++e) {
      int d = j*8 + e;
      o0[e] = (x0[e] - mu)*rstd*gamma[d]   + beta[d];
      o1[e] = (x1[e] - mu)*rstd*gamma[d+4] + beta[d+4];
    }
    *reinterpret_cast<f32x4*>(op)     = o0;
    *reinterpret_cast<f32x4*>(op + 4) = o1;
  }
}

extern "C" void kernel_launch(void* const* d_in, const int* in_sizes, int n_in,
                              void* d_out, int out_size, void* d_ws, size_t ws_size,
                              hipStream_t stream) {
  const float* lob    = (const float*)d_in[0];
  const float* hawkes = (const float*)d_in[1];
  const float* Wp     = (const float*)d_in[2];
  const float* bp     = (const float*)d_in[3];
  const float* Win    = (const float*)d_in[4];
  const float* binp   = (const float*)d_in[5];
  const float* Wo     = (const float*)d_in[6];
  const float* bo     = (const float*)d_in[7];
  const float* gamma  = (const float*)d_in[8];
  const float* beta   = (const float*)d_in[9];
  float* outg = (float*)d_out;
  float* attn_out = outg + (size_t)BT*128;   // out (B,T,128) then attn_w (B,T,T)

  char* ws = (char*)d_ws;
  bf16*  qg   = (bf16*)(ws);                                   // 4 MB
  bf16*  kg   = (bf16*)(ws + (size_t)4*1024*1024);             // 4 MB
  bf16*  vtg  = (bf16*)(ws + (size_t)8*1024*1024);             // 4 MB (B,H,32,T)
  bf16*  wb   = (bf16*)(ws + (size_t)12*1024*1024);            // 140 KB weights

  prep_kernel<<<68, 256, 0, stream>>>(Wp, Win, Wo, wb);
  proj_kernel<<<BT/32, 256, 0, stream>>>(lob, hawkes, wb, bp, binp, qg, kg, vtg);
  attn_kernel<<<BB*(TT/32), 512, 0, stream>>>(qg, kg, vtg, attn_out,
                                              lob, wb, bo, gamma, beta, outg);
}